// Round 2
// baseline (224.768 us; speedup 1.0000x reference)
//
#include <hip/hip_runtime.h>
#include <stdint.h>

#define NB 4
#define NC 256
#define NH 60
#define NW 80
#define NN (NH*NW)   // 4800

#define M_POS 1.0f
#define M_NEG 0.2f
#define THR2  64.0f  // THRESHOLD^2

typedef __attribute__((ext_vector_type(8))) short bf16x8;
typedef __attribute__((ext_vector_type(4))) float f32x4;

// ws layout (bytes):
//      0 : accum (float)
//   1024 : warped [B][N][2] float   (153600 B)
// 154624 : Abf [B][N][C] bf16       (9830400 B)
// 9985024: Bbf [B][N][C] bf16       (9830400 B)
#define WARPED_OFF 1024
#define ABF_OFF    154624
#define BBF_OFF    9985024

__device__ __forceinline__ unsigned short f2bf(float f) {
  uint32_t u = __float_as_uint(f);
  uint32_t r = (u + 0x7FFFu + ((u >> 16) & 1u)) >> 16;  // RNE
  return (unsigned short)r;
}

// ---------------- warp centers by homography ----------------
__global__ void warp_kernel(const float* __restrict__ H, float* __restrict__ warped) {
  int idx = blockIdx.x * 256 + threadIdx.x;   // 0..19199
  if (idx >= NB * NN) return;
  int b = idx / NN, n = idx % NN;
  int i = n / NW, j = n % NW;
  float x = j * 8.0f + 4.0f;
  float y = i * 8.0f + 4.0f;
  const float* h = H + b * 9;
  float w0 = h[0]*x + h[1]*y + h[2];
  float w1 = h[3]*x + h[4]*y + h[5];
  float w2 = h[6]*x + h[7]*y + h[8];
  warped[idx*2 + 0] = w0 / w2;
  warped[idx*2 + 1] = w1 / w2;
}

// ---------------- transpose [C][N] f32 -> [N][C] bf16 ----------------
__global__ void tconv_kernel(const float* __restrict__ da, const float* __restrict__ db,
                             unsigned short* __restrict__ Abf, unsigned short* __restrict__ Bbf) {
  int t = blockIdx.x;              // 0..2399 = 2 tensors * 4 b * 4 ct * 75 nt
  int tensor = t / 1200; int rem = t % 1200;
  int b  = rem / 300;    int rem2 = rem % 300;
  int ct = rem2 / 75,    nt = rem2 % 75;
  int c0 = ct * 64, n0 = nt * 64;
  const float* in = (tensor ? db : da) + ((size_t)b * NC + c0) * NN + n0;
  unsigned short* out = (tensor ? Bbf : Abf) + ((size_t)b * NN + n0) * NC + c0;

  __shared__ float tile[64][65];
  int tr = threadIdx.x >> 6, tc = threadIdx.x & 63;
  #pragma unroll
  for (int i = 0; i < 16; ++i) {
    int c = i * 4 + tr;
    tile[c][tc] = in[(size_t)c * NN + tc];
  }
  __syncthreads();
  #pragma unroll
  for (int i = 0; i < 16; ++i) {
    int n = i * 4 + tr;
    out[(size_t)n * NC + tc] = f2bf(tile[tc][n]);
  }
}

// ---------------- fused GEMM + mask + hinge loss + reduce ----------------
// block tile 160x160, 4 waves (2x2), per-wave 80x80 = 5x5 frags of 16x16x32
// K = 256 staged in 8 chunks of BK=32, double-buffered LDS, prefetch-1
#define BM 160
#define BK 32

__global__ __launch_bounds__(256) __attribute__((amdgpu_waves_per_eu(2, 2)))
void gemm_loss_kernel(
    const unsigned short* __restrict__ Abf, const unsigned short* __restrict__ Bbf,
    const float* __restrict__ warped, float* __restrict__ accum) {
  // [2 buffers][160 rows][32 k] bf16 per tensor; 10 KiB per buffer per tensor = 40 KiB
  __shared__ unsigned short lds_a[2][BM * BK];
  __shared__ unsigned short lds_b[2][BM * BK];

  int bid = blockIdx.x;            // 0..3599
  int b = bid / 900; int r = bid % 900;
  int tn = r / 30, tm = r % 30;
  int n0 = tn * BM, m0 = tm * BM;

  int tid = threadIdx.x;
  int w = tid >> 6, l = tid & 63;
  int wr = w >> 1, wc = w & 1;

  const unsigned short* Ab = Abf + (size_t)b * NN * NC;
  const unsigned short* Bb = Bbf + (size_t)b * NN * NC;

  f32x4 acc[5][5];
  #pragma unroll
  for (int i = 0; i < 5; ++i)
    #pragma unroll
    for (int j = 0; j < 5; ++j)
      acc[i][j] = (f32x4){0.f, 0.f, 0.f, 0.f};

  // stage one BK=32 chunk (A tile + B tile) into buffer `buf`
  // combined chunk space: 20 groups of 64 x 16B chunks; wave w -> groups w*5..w*5+4
  // groups 0..9 = A (160x4), 10..19 = B. Linear LDS dest; XOR-swizzled SOURCE.
  auto stage = [&](int kb, int buf) {
    #pragma unroll
    for (int i = 0; i < 5; ++i) {
      int g = w * 5 + i;                 // wave-uniform
      if (g < 10) {
        int cid = g * 64 + l;            // 0..639
        int row = cid >> 2, col = cid & 3;
        int scol = col ^ ((row >> 1) & 3);
        const unsigned short* ga = Ab + (size_t)(n0 + row) * NC + kb * BK + scol * 8;
        __builtin_amdgcn_global_load_lds(
            (const __attribute__((address_space(1))) uint32_t*)ga,
            (__attribute__((address_space(3))) uint32_t*)&lds_a[buf][g * 512], 16, 0, 0);
      } else {
        int cid = (g - 10) * 64 + l;
        int row = cid >> 2, col = cid & 3;
        int scol = col ^ ((row >> 1) & 3);
        const unsigned short* gb = Bb + (size_t)(m0 + row) * NC + kb * BK + scol * 8;
        __builtin_amdgcn_global_load_lds(
            (const __attribute__((address_space(1))) uint32_t*)gb,
            (__attribute__((address_space(3))) uint32_t*)&lds_b[buf][(g - 10) * 512], 16, 0, 0);
      }
    }
  };

  stage(0, 0);
  __syncthreads();

  for (int kb = 0; kb < 8; ++kb) {
    int cur = kb & 1;
    if (kb < 7) stage(kb + 1, cur ^ 1);   // prefetch next chunk into other buffer

    bf16x8 af[5], bfr[5];
    int c = l >> 4;
    #pragma unroll
    for (int i = 0; i < 5; ++i) {
      int rowa = wr * 80 + i * 16 + (l & 15);
      int ca = c ^ ((rowa >> 1) & 3);      // same involution on READ
      af[i] = *(const bf16x8*)&lds_a[cur][rowa * 32 + ca * 8];
      int rowb = wc * 80 + i * 16 + (l & 15);
      int cb = c ^ ((rowb >> 1) & 3);
      bfr[i] = *(const bf16x8*)&lds_b[cur][rowb * 32 + cb * 8];
    }
    #pragma unroll
    for (int i = 0; i < 5; ++i)
      #pragma unroll
      for (int j = 0; j < 5; ++j)
        acc[i][j] = __builtin_amdgcn_mfma_f32_16x16x32_bf16(af[i], bfr[j], acc[i][j], 0, 0, 0);

    __syncthreads();   // drains vmcnt (prefetch done) + syncs buffer reuse
  }

  // ---- epilogue: mask + hinge + sum
  // C/D layout: col = l&15, row = 4*(l>>4)+q
  float cxs[5], cys[5];
  #pragma unroll
  for (int j = 0; j < 5; ++j) {
    int m = m0 + wc * 80 + j * 16 + (l & 15);
    int im = m / NW;
    int jm = m - im * NW;
    cxs[j] = jm * 8.0f + 4.0f;
    cys[j] = im * 8.0f + 4.0f;
  }
  const float* wp = warped + (size_t)b * NN * 2;
  float lsum = 0.0f;
  #pragma unroll
  for (int i = 0; i < 5; ++i) {
    int nbase = n0 + wr * 80 + i * 16 + ((l >> 4) << 2);
    #pragma unroll
    for (int q = 0; q < 4; ++q) {
      float wx = wp[(size_t)(nbase + q) * 2 + 0];
      float wy = wp[(size_t)(nbase + q) * 2 + 1];
      #pragma unroll
      for (int j = 0; j < 5; ++j) {
        float sim = acc[i][j][q];
        float dx = wx - cxs[j];
        float dy = wy - cys[j];
        bool pos = (dx * dx + dy * dy) <= THR2;
        float loss = pos ? fmaxf(M_POS - sim, 0.0f) : fmaxf(sim - M_NEG, 0.0f);
        lsum += loss;
      }
    }
  }
  #pragma unroll
  for (int off = 32; off > 0; off >>= 1)
    lsum += __shfl_xor(lsum, off);
  if (l == 0) atomicAdd(accum, lsum);
}

__global__ void finalize_kernel(const float* __restrict__ accum, float* __restrict__ out) {
  out[0] = accum[0] * (1.0f / ((float)NB * (float)NN * (float)NN));
}

extern "C" void kernel_launch(void* const* d_in, const int* in_sizes, int n_in,
                              void* d_out, int out_size, void* d_ws, size_t ws_size,
                              hipStream_t stream) {
  const float* da = (const float*)d_in[0];
  const float* db = (const float*)d_in[1];
  const float* H  = (const float*)d_in[2];
  // d_in[3] = valid_mask (all ones, unused by the reference math)

  char* ws = (char*)d_ws;
  float* accum = (float*)ws;
  float* warped = (float*)(ws + WARPED_OFF);
  unsigned short* Abf = (unsigned short*)(ws + ABF_OFF);
  unsigned short* Bbf = (unsigned short*)(ws + BBF_OFF);

  hipMemsetAsync(accum, 0, 4, stream);
  warp_kernel<<<75, 256, 0, stream>>>(H, warped);
  tconv_kernel<<<2400, 256, 0, stream>>>(da, db, Abf, Bbf);
  gemm_loss_kernel<<<3600, 256, 0, stream>>>(Abf, Bbf, warped, accum);
  finalize_kernel<<<1, 1, 0, stream>>>(accum, (float*)d_out);
}

// Round 3
// 94.951 us; speedup vs baseline: 2.3672x; 2.3672x over previous
//
#include <hip/hip_runtime.h>
#include <stdint.h>

#define NB 4
#define NC 256
#define NH 60
#define NW 80
#define NN (NH*NW)   // 4800

#define M_POS 1.0f
#define M_NEG 0.2f
#define THR2  64.0f  // THRESHOLD^2

typedef __attribute__((ext_vector_type(8))) short bf16x8;
typedef __attribute__((ext_vector_type(4))) float f32x4;

// ws layout (bytes):
//      0 : slots[256] float (partial accumulators)
//   1024 : warped [B][N][2] float   (153600 B)
// 154624 : Abf [B][N][C] bf16       (9830400 B)
// 9985024: Bbf [B][N][C] bf16       (9830400 B)
#define WARPED_OFF 1024
#define ABF_OFF    154624
#define BBF_OFF    9985024

__device__ __forceinline__ unsigned short f2bf(float f) {
  uint32_t u = __float_as_uint(f);
  uint32_t r = (u + 0x7FFFu + ((u >> 16) & 1u)) >> 16;  // RNE
  return (unsigned short)r;
}

// ---------------- warp centers by homography ----------------
__global__ void warp_kernel(const float* __restrict__ H, float* __restrict__ warped) {
  int idx = blockIdx.x * 256 + threadIdx.x;   // 0..19199
  if (idx >= NB * NN) return;
  int b = idx / NN, n = idx % NN;
  int i = n / NW, j = n % NW;
  float x = j * 8.0f + 4.0f;
  float y = i * 8.0f + 4.0f;
  const float* h = H + b * 9;
  float w0 = h[0]*x + h[1]*y + h[2];
  float w1 = h[3]*x + h[4]*y + h[5];
  float w2 = h[6]*x + h[7]*y + h[8];
  warped[idx*2 + 0] = w0 / w2;
  warped[idx*2 + 1] = w1 / w2;
}

// ---------------- transpose [C][N] f32 -> [N][C] bf16 ----------------
__global__ void tconv_kernel(const float* __restrict__ da, const float* __restrict__ db,
                             unsigned short* __restrict__ Abf, unsigned short* __restrict__ Bbf) {
  int t = blockIdx.x;              // 0..2399 = 2 tensors * 4 b * 4 ct * 75 nt
  int tensor = t / 1200; int rem = t % 1200;
  int b  = rem / 300;    int rem2 = rem % 300;
  int ct = rem2 / 75,    nt = rem2 % 75;
  int c0 = ct * 64, n0 = nt * 64;
  const float* in = (tensor ? db : da) + ((size_t)b * NC + c0) * NN + n0;
  unsigned short* out = (tensor ? Bbf : Abf) + ((size_t)b * NN + n0) * NC + c0;

  __shared__ float tile[64][65];
  int tr = threadIdx.x >> 6, tc = threadIdx.x & 63;
  #pragma unroll
  for (int i = 0; i < 16; ++i) {
    int c = i * 4 + tr;
    tile[c][tc] = in[(size_t)c * NN + tc];
  }
  __syncthreads();
  #pragma unroll
  for (int i = 0; i < 16; ++i) {
    int n = i * 4 + tr;
    out[(size_t)n * NC + tc] = f2bf(tile[tc][n]);
  }
}

// ---------------- fused GEMM + mask + hinge loss + reduce ----------------
// block tile 96x96, 4 waves (2x2), per-wave 48x48 = 3x3 frags of 16x16x32
// K = 256 in 4 chunks of BK=64; static double-buffer, fully unrolled pipeline
#define BM 96
#define BK 64

// stage one BK=64 chunk of A and B tiles into LA/LB (linear LDS dest,
// XOR-swizzled global SOURCE: scol = col ^ (row&7), involution)
#define STAGE(kb, LA, LB) do {                                                       \
    _Pragma("unroll")                                                                \
    for (int i_ = 0; i_ < 3; ++i_) {                                                 \
      int cid_ = w * 192 + i_ * 64 + l;                                              \
      int row_ = cid_ >> 3, col_ = cid_ & 7;                                         \
      int scol_ = col_ ^ (row_ & 7);                                                 \
      const unsigned short* ga_ = Ab + (size_t)(n0 + row_) * NC + (kb) * BK + scol_ * 8; \
      __builtin_amdgcn_global_load_lds(                                              \
          (const __attribute__((address_space(1))) uint32_t*)ga_,                    \
          (__attribute__((address_space(3))) uint32_t*)&LA[(w * 192 + i_ * 64) * 8], \
          16, 0, 0);                                                                 \
      const unsigned short* gb_ = Bb + (size_t)(m0 + row_) * NC + (kb) * BK + scol_ * 8; \
      __builtin_amdgcn_global_load_lds(                                              \
          (const __attribute__((address_space(1))) uint32_t*)gb_,                    \
          (__attribute__((address_space(3))) uint32_t*)&LB[(w * 192 + i_ * 64) * 8], \
          16, 0, 0);                                                                 \
    }                                                                                \
  } while (0)

#define COMPUTE(LA, LB) do {                                                         \
    _Pragma("unroll")                                                                \
    for (int kk_ = 0; kk_ < 2; ++kk_) {                                              \
      bf16x8 af_[3], bf_[3];                                                         \
      int c_ = kk_ * 4 + (l >> 4);                                                   \
      _Pragma("unroll")                                                              \
      for (int i_ = 0; i_ < 3; ++i_) {                                               \
        int rowa_ = wr * 48 + i_ * 16 + (l & 15);                                    \
        af_[i_] = *(const bf16x8*)&LA[(rowa_ * 8 + (c_ ^ (rowa_ & 7))) * 8];         \
        int rowb_ = wc * 48 + i_ * 16 + (l & 15);                                    \
        bf_[i_] = *(const bf16x8*)&LB[(rowb_ * 8 + (c_ ^ (rowb_ & 7))) * 8];         \
      }                                                                              \
      _Pragma("unroll")                                                              \
      for (int i_ = 0; i_ < 3; ++i_)                                                 \
        _Pragma("unroll")                                                            \
        for (int j_ = 0; j_ < 3; ++j_)                                               \
          acc[i_][j_] = __builtin_amdgcn_mfma_f32_16x16x32_bf16(af_[i_], bf_[j_],    \
                                                                acc[i_][j_], 0, 0, 0); \
    }                                                                                \
  } while (0)

__global__ __launch_bounds__(256) void gemm_loss_kernel(
    const unsigned short* __restrict__ Abf, const unsigned short* __restrict__ Bbf,
    const float* __restrict__ warped, float* __restrict__ slots) {
  __shared__ unsigned short la0[BM * BK], la1[BM * BK];
  __shared__ unsigned short lb0[BM * BK], lb1[BM * BK];
  __shared__ float red[4];

  int bid = blockIdx.x;            // 0..9999
  int b = bid / 2500; int r = bid % 2500;
  int tn = r / 50, tm = r % 50;
  int n0 = tn * BM, m0 = tm * BM;

  int tid = threadIdx.x;
  int w = tid >> 6, l = tid & 63;
  int wr = w >> 1, wc = w & 1;

  const unsigned short* Ab = Abf + (size_t)b * NN * NC;
  const unsigned short* Bb = Bbf + (size_t)b * NN * NC;

  f32x4 acc[3][3];
  #pragma unroll
  for (int i = 0; i < 3; ++i)
    #pragma unroll
    for (int j = 0; j < 3; ++j)
      acc[i][j] = (f32x4){0.f, 0.f, 0.f, 0.f};

  // ---- unrolled 4-chunk pipeline, prefetch-1, static buffers
  STAGE(0, la0, lb0);
  __syncthreads();
  STAGE(1, la1, lb1);
  COMPUTE(la0, lb0);
  __syncthreads();
  STAGE(2, la0, lb0);
  COMPUTE(la1, lb1);
  __syncthreads();
  STAGE(3, la1, lb1);
  COMPUTE(la0, lb0);
  __syncthreads();
  COMPUTE(la1, lb1);

  // ---- epilogue: mask + hinge + sum
  // C/D layout: col = l&15, row = 4*(l>>4)+q
  float cxs[3], cys[3];
  #pragma unroll
  for (int j = 0; j < 3; ++j) {
    int m = m0 + wc * 48 + j * 16 + (l & 15);
    int im = m / NW;
    int jm = m - im * NW;
    cxs[j] = jm * 8.0f + 4.0f;
    cys[j] = im * 8.0f + 4.0f;
  }
  const float* wp = warped + (size_t)b * NN * 2;
  float lsum = 0.0f;
  #pragma unroll
  for (int i = 0; i < 3; ++i) {
    int nbase = n0 + wr * 48 + i * 16 + ((l >> 4) << 2);
    #pragma unroll
    for (int q = 0; q < 4; ++q) {
      float wx = wp[(size_t)(nbase + q) * 2 + 0];
      float wy = wp[(size_t)(nbase + q) * 2 + 1];
      #pragma unroll
      for (int j = 0; j < 3; ++j) {
        float sim = acc[i][j][q];
        float dx = wx - cxs[j];
        float dy = wy - cys[j];
        bool pos = (dx * dx + dy * dy) <= THR2;
        float loss = pos ? fmaxf(M_POS - sim, 0.0f) : fmaxf(sim - M_NEG, 0.0f);
        lsum += loss;
      }
    }
  }
  #pragma unroll
  for (int off = 32; off > 0; off >>= 1)
    lsum += __shfl_xor(lsum, off);
  if (l == 0) red[w] = lsum;
  __syncthreads();
  if (tid == 0)
    atomicAdd(&slots[bid & 255], red[0] + red[1] + red[2] + red[3]);
}

__global__ void finalize_kernel(const float* __restrict__ slots, float* __restrict__ out) {
  float v = slots[threadIdx.x];                 // 256 threads, one slot each
  #pragma unroll
  for (int off = 32; off > 0; off >>= 1)
    v += __shfl_xor(v, off);
  __shared__ float red[4];
  if ((threadIdx.x & 63) == 0) red[threadIdx.x >> 6] = v;
  __syncthreads();
  if (threadIdx.x == 0)
    out[0] = (red[0] + red[1] + red[2] + red[3]) * (1.0f / ((float)NB * (float)NN * (float)NN));
}

extern "C" void kernel_launch(void* const* d_in, const int* in_sizes, int n_in,
                              void* d_out, int out_size, void* d_ws, size_t ws_size,
                              hipStream_t stream) {
  const float* da = (const float*)d_in[0];
  const float* db = (const float*)d_in[1];
  const float* H  = (const float*)d_in[2];
  // d_in[3] = valid_mask (all ones, unused by the reference math)

  char* ws = (char*)d_ws;
  float* slots  = (float*)ws;
  float* warped = (float*)(ws + WARPED_OFF);
  unsigned short* Abf = (unsigned short*)(ws + ABF_OFF);
  unsigned short* Bbf = (unsigned short*)(ws + BBF_OFF);

  hipMemsetAsync(slots, 0, 1024, stream);
  warp_kernel<<<75, 256, 0, stream>>>(H, warped);
  tconv_kernel<<<2400, 256, 0, stream>>>(da, db, Abf, Bbf);
  gemm_loss_kernel<<<10000, 256, 0, stream>>>(Abf, Bbf, warped, slots);
  finalize_kernel<<<1, 256, 0, stream>>>(slots, (float*)d_out);
}